// Round 9
// baseline (813.128 us; speedup 1.0000x reference)
//
#include <hip/hip_runtime.h>

#define N_NODES 100000
#define N_PAD   100352        // 392*256
#define N_EDGES 3200000
#define IN_DIM  128
#define HID     64
#define N_GRAPHS 256
#define NB      392           // buckets of 256 dest nodes each
#define NBLK    256           // hist/scatter blocks
#define EPB     (N_EDGES / NBLK)   // 12500

typedef unsigned short ushort_t;
typedef unsigned int   uint_t;

// bf16 helpers: storage-only compression of the gathered operand
__device__ __forceinline__ ushort_t f2bf(float v) {          // round-to-nearest-even
    uint_t b = __float_as_uint(v);
    b += 0x7fffu + ((b >> 16) & 1u);
    return (ushort_t)(b >> 16);
}
__device__ __forceinline__ void bf2f2(uint_t u, float& lo, float& hi) {
    lo = __uint_as_float(u << 16);
    hi = __uint_as_float(u & 0xffff0000u);
}
// 16B load -> 8 floats
__device__ __forceinline__ void ld_bf16x8(const ushort_t* p, float4& a, float4& b) {
    uint4 u = *(const uint4*)p;
    bf2f2(u.x, a.x, a.y); bf2f2(u.y, a.z, a.w);
    bf2f2(u.z, b.x, b.y); bf2f2(u.w, b.z, b.w);
}

// ---------- phase 1: per-block bucket histogram (LDS only, no global atomics) ----------
__global__ __launch_bounds__(256) void bhist_kernel(const int* __restrict__ col,
                                                    int* __restrict__ H) {
    __shared__ int h[NB];
    for (int i = threadIdx.x; i < NB; i += 256) h[i] = 0;
    __syncthreads();
    const int4* col4 = (const int4*)col;
    int base4 = blockIdx.x * (EPB / 4);
    for (int j = threadIdx.x; j < EPB / 4; j += 256) {
        int4 c = col4[base4 + j];
        atomicAdd(&h[c.x >> 8], 1);
        atomicAdd(&h[c.y >> 8], 1);
        atomicAdd(&h[c.z >> 8], 1);
        atomicAdd(&h[c.w >> 8], 1);
    }
    __syncthreads();
    for (int i = threadIdx.x; i < NB; i += 256) H[i * NBLK + blockIdx.x] = h[i];
}

// ---------- phase 2: exclusive scan of H (NB*NBLK, bucket-major) ----------
__global__ __launch_bounds__(256) void scan1_kernel(int* H, int* __restrict__ bsum) {
    __shared__ int s[256];
    int i = blockIdx.x * 256 + threadIdx.x;   // blockIdx.x == bucket (NBLK==256)
    int v = H[i];
    s[threadIdx.x] = v;
    __syncthreads();
    #pragma unroll
    for (int off = 1; off < 256; off <<= 1) {
        int t = (threadIdx.x >= off) ? s[threadIdx.x - off] : 0;
        __syncthreads();
        s[threadIdx.x] += t;
        __syncthreads();
    }
    H[i] = s[threadIdx.x] - v;                           // exclusive within bucket
    if (threadIdx.x == 255) bsum[blockIdx.x] = s[255];   // bucket total
}

__global__ __launch_bounds__(256) void scan2_kernel(const int* __restrict__ bsum,
                                                    int* __restrict__ boff) {
    __shared__ int s[256];
    __shared__ int carry;
    if (threadIdx.x == 0) carry = 0;
    __syncthreads();
    for (int c = 0; c < (NB + 255) / 256; ++c) {
        int i = c * 256 + threadIdx.x;
        int v = (i < NB) ? bsum[i] : 0;
        s[threadIdx.x] = v;
        __syncthreads();
        #pragma unroll
        for (int off = 1; off < 256; off <<= 1) {
            int t = (threadIdx.x >= off) ? s[threadIdx.x - off] : 0;
            __syncthreads();
            s[threadIdx.x] += t;
            __syncthreads();
        }
        if (i < NB) boff[i] = s[threadIdx.x] - v + carry;   // bucket start offsets
        __syncthreads();
        if (threadIdx.x == 0) carry += s[255];
        __syncthreads();
    }
}

// ---------- phase 3: scatter records to bucket-contiguous; cursors in LDS ----------
// rec = (row | local<<17, ew); local = col & 255 (8 bits), row < 2^17
__global__ __launch_bounds__(256) void bscatter_kernel(const int* __restrict__ row,
                                                       const int* __restrict__ col,
                                                       const float* __restrict__ ew,
                                                       const int* __restrict__ H,
                                                       const int* __restrict__ boff,
                                                       int2* __restrict__ recs) {
    __shared__ int cur[NB];
    for (int i = threadIdx.x; i < NB; i += 256)
        cur[i] = H[i * NBLK + blockIdx.x] + boff[i];      // fused scan3
    __syncthreads();
    const int4*   row4 = (const int4*)row;
    const int4*   col4 = (const int4*)col;
    const float4* ew4  = (const float4*)ew;
    int base4 = blockIdx.x * (EPB / 4);
    for (int j = threadIdx.x; j < EPB / 4; j += 256) {
        int4   r4 = row4[base4 + j];
        int4   c4 = col4[base4 + j];
        float4 w4 = ew4[base4 + j];
        int p0 = atomicAdd(&cur[c4.x >> 8], 1);
        recs[p0] = make_int2(r4.x | ((c4.x & 255) << 17), __float_as_int(w4.x));
        int p1 = atomicAdd(&cur[c4.y >> 8], 1);
        recs[p1] = make_int2(r4.y | ((c4.y & 255) << 17), __float_as_int(w4.y));
        int p2 = atomicAdd(&cur[c4.z >> 8], 1);
        recs[p2] = make_int2(r4.z | ((c4.z & 255) << 17), __float_as_int(w4.z));
        int p3 = atomicAdd(&cur[c4.w >> 8], 1);
        recs[p3] = make_int2(r4.w | ((c4.w & 255) << 17), __float_as_int(w4.w));
    }
}

// ---------- phase 3.5: deg/dis per bucket from recs (LDS accumulation) ----------
__global__ __launch_bounds__(256) void degdis_kernel(const int2* __restrict__ recs,
                                                     const int* __restrict__ boff,
                                                     float* __restrict__ dis) {
    __shared__ float degf[256];
    int b = blockIdx.x, tid = threadIdx.x;
    degf[tid] = 0.f;
    __syncthreads();
    int s = boff[b], e = (b + 1 < NB) ? boff[b + 1] : N_EDGES;
    for (int j = s + tid; j < e; j += 256) {
        int2 r = recs[j];
        atomicAdd(&degf[(r.x >> 17) & 255], __int_as_float(r.y));
    }
    __syncthreads();
    dis[b * 256 + tid] = 1.0f / sqrtf(fmaxf(1.0f + degf[tid], 1e-30f));
}

// ---------- phase 4: per-bucket counting sort -> per-node CSR; FULL weight folded ----
// csr[pos] = (row, dis[row] * ew * dis[col])
__global__ __launch_bounds__(256) void bsort_kernel(const int2* __restrict__ recs,
                                                    const int* __restrict__ boff,
                                                    const float* __restrict__ dis,
                                                    float2* __restrict__ csr,
                                                    int* __restrict__ rowptr) {
    __shared__ int   cnt[256];
    __shared__ int   cur[256];
    __shared__ float sdis[256];
    __shared__ int   sscan[256];
    int b = blockIdx.x, tid = threadIdx.x;
    cnt[tid] = 0;
    sdis[tid] = dis[b * 256 + tid];
    __syncthreads();
    int s = boff[b], e = (b + 1 < NB) ? boff[b + 1] : N_EDGES;
    for (int j = s + tid; j < e; j += 256) {
        int2 r = recs[j];
        atomicAdd(&cnt[(r.x >> 17) & 255], 1);
    }
    __syncthreads();
    int c = cnt[tid];
    sscan[tid] = c;
    __syncthreads();
    #pragma unroll
    for (int off = 1; off < 256; off <<= 1) {
        int t = (tid >= off) ? sscan[tid - off] : 0;
        __syncthreads();
        sscan[tid] += t;
        __syncthreads();
    }
    int excl = sscan[tid] - c;
    cur[tid] = excl;
    rowptr[b * 256 + tid] = s + excl;    // trailing zero-cnt nodes give rowptr[N]=E
    __syncthreads();
    for (int j = s + tid; j < e; j += 256) {
        int2 r = recs[j];
        int cl = (r.x >> 17) & 255;
        int rr = r.x & 0x1FFFF;
        int pos = s + atomicAdd(&cur[cl], 1);
        csr[pos] = make_float2(__int_as_float(rr),
                               dis[rr] * __int_as_float(r.y) * sdis[cl]);
    }
}

// ---------- layer 1 GEMM: xl = x @ W1 (bf16 output) ----------
__global__ __launch_bounds__(256) void gemm1_kernel(const float* __restrict__ x,
                                                    const float* __restrict__ W1,
                                                    ushort_t* __restrict__ xl) {
    __shared__ float sW[IN_DIM * HID];   // 32 KB
    __shared__ float sx[4][IN_DIM];
    int tid = threadIdx.x;
    const float4* W4  = (const float4*)W1;
    float4*       sW4 = (float4*)sW;
    #pragma unroll
    for (int i = 0; i < 8; ++i) sW4[tid + 256 * i] = W4[tid + 256 * i];
    int r0 = blockIdx.x * 4;
    const float4* x4  = (const float4*)(x + (size_t)r0 * IN_DIM);
    float4*       sx4 = (float4*)&sx[0][0];
    if (tid < 128) sx4[tid] = x4[tid];
    __syncthreads();
    int lr = tid >> 6, c = tid & 63;
    float acc = 0.f;
    #pragma unroll 8
    for (int k = 0; k < IN_DIM; ++k) acc += sx[lr][k] * sW[k * HID + c];
    xl[(size_t)(r0 + lr) * HID + c] = f2bf(acc);
}

// ---------- gather core: 8-lane groups, 16B loads, 4 edges in flight/group ----------
// lanes 0..7 hold the final 64-channel row (8 channels each) after reduction
__device__ __forceinline__ void gather_row(const float2* __restrict__ csr,
                                           const ushort_t* __restrict__ xl,
                                           int base, int end, int n, float d2,
                                           int g, int c0,
                                           float4& a0, float4& a1) {
    a0 = make_float4(0.f, 0.f, 0.f, 0.f);
    a1 = make_float4(0.f, 0.f, 0.f, 0.f);
    if (g == 0) {
        float4 s0, s1;
        ld_bf16x8(xl + (size_t)n * HID + c0, s0, s1);
        a0.x = s0.x * d2; a0.y = s0.y * d2; a0.z = s0.z * d2; a0.w = s0.w * d2;
        a1.x = s1.x * d2; a1.y = s1.y * d2; a1.z = s1.z * d2; a1.w = s1.w * d2;
    }
    int j = base + g;
    for (; j + 24 < end; j += 32) {                      // 4 edges in flight
        float2 e0 = csr[j];
        float2 e1 = csr[j + 8];
        float2 e2 = csr[j + 16];
        float2 e3 = csr[j + 24];
        int r0_ = __float_as_int(e0.x), r1_ = __float_as_int(e1.x);
        int r2_ = __float_as_int(e2.x), r3_ = __float_as_int(e3.x);
        float4 xa0, xa1, xb0, xb1, xc0, xc1, xd0, xd1;
        ld_bf16x8(xl + (size_t)r0_ * HID + c0, xa0, xa1);
        ld_bf16x8(xl + (size_t)r1_ * HID + c0, xb0, xb1);
        ld_bf16x8(xl + (size_t)r2_ * HID + c0, xc0, xc1);
        ld_bf16x8(xl + (size_t)r3_ * HID + c0, xd0, xd1);
        a0.x += xa0.x * e0.y + xb0.x * e1.y + xc0.x * e2.y + xd0.x * e3.y;
        a0.y += xa0.y * e0.y + xb0.y * e1.y + xc0.y * e2.y + xd0.y * e3.y;
        a0.z += xa0.z * e0.y + xb0.z * e1.y + xc0.z * e2.y + xd0.z * e3.y;
        a0.w += xa0.w * e0.y + xb0.w * e1.y + xc0.w * e2.y + xd0.w * e3.y;
        a1.x += xa1.x * e0.y + xb1.x * e1.y + xc1.x * e2.y + xd1.x * e3.y;
        a1.y += xa1.y * e0.y + xb1.y * e1.y + xc1.y * e2.y + xd1.y * e3.y;
        a1.z += xa1.z * e0.y + xb1.z * e1.y + xc1.z * e2.y + xd1.z * e3.y;
        a1.w += xa1.w * e0.y + xb1.w * e1.y + xc1.w * e2.y + xd1.w * e3.y;
    }
    for (; j < end; j += 8) {
        float2 e0 = csr[j];
        int ra = __float_as_int(e0.x);
        float w0 = e0.y;
        float4 xa0, xa1;
        ld_bf16x8(xl + (size_t)ra * HID + c0, xa0, xa1);
        a0.x += xa0.x * w0; a0.y += xa0.y * w0; a0.z += xa0.z * w0; a0.w += xa0.w * w0;
        a1.x += xa1.x * w0; a1.y += xa1.y * w0; a1.z += xa1.z * w0; a1.w += xa1.w * w0;
    }
    #pragma unroll
    for (int o = 32; o >= 8; o >>= 1) {
        a0.x += __shfl_down(a0.x, o, 64); a0.y += __shfl_down(a0.y, o, 64);
        a0.z += __shfl_down(a0.z, o, 64); a0.w += __shfl_down(a0.w, o, 64);
        a1.x += __shfl_down(a1.x, o, 64); a1.y += __shfl_down(a1.y, o, 64);
        a1.z += __shfl_down(a1.z, o, 64); a1.w += __shfl_down(a1.w, o, 64);
    }
}

// ---------- fused gather1 + gemm2: xl2 = relu(gather(xl1) + b1) @ W2 (bf16 out) ----------
__global__ __launch_bounds__(256) void gather_gemm2_kernel(
        const float2* __restrict__ csr, const int* __restrict__ rowptr,
        const float* __restrict__ dis, const ushort_t* __restrict__ xl,
        const float* __restrict__ W2, const float* __restrict__ b1,
        ushort_t* __restrict__ xl2) {
    __shared__ float sW[HID * HID];   // 16 KB
    __shared__ float sh[4][HID];
    __shared__ float sb1[HID];
    int tid = threadIdx.x;
    const float4* W4  = (const float4*)W2;
    float4*       sW4 = (float4*)sW;
    #pragma unroll
    for (int i = 0; i < 4; ++i) sW4[tid + 256 * i] = W4[tid + 256 * i];
    if (tid < HID) sb1[tid] = b1[tid];

    int r0   = blockIdx.x * 4;
    int wv   = tid >> 6;
    int n    = r0 + wv;
    int lane = tid & 63;
    int g    = lane >> 3;
    int c0   = (lane & 7) << 3;
    int base = rowptr[n], end = rowptr[n + 1];
    float d  = dis[n];
    float4 a0, a1;
    gather_row(csr, xl, base, end, n, d * d, g, c0, a0, a1);
    if (lane < 8) {
        *(float4*)(&sh[wv][c0])     = a0;
        *(float4*)(&sh[wv][c0 + 4]) = a1;
    }
    __syncthreads();                                    // sW, sb1, sh all visible
    int lr = wv, cc = lane;
    float hv = fmaxf(sh[lr][cc] + sb1[cc], 0.f);        // relu(agg1 + b1)
    __syncthreads();
    sh[lr][cc] = hv;
    __syncthreads();
    float acc2 = 0.f;
    #pragma unroll 8
    for (int k = 0; k < HID; ++k) acc2 += sh[lr][k] * sW[k * HID + cc];
    xl2[(size_t)(r0 + lr) * HID + cc] = f2bf(acc2);
}

// ---------- fused gather2 + pool + head partial ----------
// s[n] = sum_c relu(agg2[n][c] + b2[c]) * Wc[c];  out_acc[batch[n]] += s[n]
__global__ __launch_bounds__(256) void gather_pool_kernel(
        const float2* __restrict__ csr, const int* __restrict__ rowptr,
        const float* __restrict__ dis, const ushort_t* __restrict__ xl,
        const float* __restrict__ b2, const float* __restrict__ Wc,
        const int* __restrict__ batch, float* out_acc) {
    int tid  = threadIdx.x;
    int n    = (blockIdx.x * 256 + tid) >> 6;           // grid 25000 exact
    int lane = tid & 63;
    int g    = lane >> 3;
    int c0   = (lane & 7) << 3;
    int base = rowptr[n], end = rowptr[n + 1];
    float d  = dis[n];
    float4 a0, a1;
    gather_row(csr, xl, base, end, n, d * d, g, c0, a0, a1);
    if (lane < 8) {
        float4 bb0 = *(const float4*)(b2 + c0);
        float4 bb1 = *(const float4*)(b2 + c0 + 4);
        float4 wc0 = *(const float4*)(Wc + c0);
        float4 wc1 = *(const float4*)(Wc + c0 + 4);
        float s = fmaxf(a0.x + bb0.x, 0.f) * wc0.x + fmaxf(a0.y + bb0.y, 0.f) * wc0.y
                + fmaxf(a0.z + bb0.z, 0.f) * wc0.z + fmaxf(a0.w + bb0.w, 0.f) * wc0.w
                + fmaxf(a1.x + bb1.x, 0.f) * wc1.x + fmaxf(a1.y + bb1.y, 0.f) * wc1.y
                + fmaxf(a1.z + bb1.z, 0.f) * wc1.z + fmaxf(a1.w + bb1.w, 0.f) * wc1.w;
        s += __shfl_down(s, 4, 64);
        s += __shfl_down(s, 2, 64);
        s += __shfl_down(s, 1, 64);
        if ((lane & 7) == 0) unsafeAtomicAdd(&out_acc[batch[n]], s);
    }
}

// ---------- final: out[g] = out_acc[g]/cnt[g] + bc ----------
__global__ __launch_bounds__(256) void final_out_kernel(const float* __restrict__ out_acc,
                                                        const int* __restrict__ batch,
                                                        const float* __restrict__ bc,
                                                        float* __restrict__ out) {
    int g = threadIdx.x;   // grid 1, 256 threads
    int lo = 0, hi = N_NODES;
    while (lo < hi) { int m = (lo + hi) >> 1; if (batch[m] < g) lo = m + 1; else hi = m; }
    int start = lo;
    hi = N_NODES;
    while (lo < hi) { int m = (lo + hi) >> 1; if (batch[m] < g + 1) lo = m + 1; else hi = m; }
    float cnt = (float)(lo - start);
    out[g] = out_acc[g] / fmaxf(cnt, 1.0f) + bc[0];
}

extern "C" void kernel_launch(void* const* d_in, const int* in_sizes, int n_in,
                              void* d_out, int out_size, void* d_ws, size_t ws_size,
                              hipStream_t stream) {
    const float* x     = (const float*)d_in[0];
    const int*   ei    = (const int*)  d_in[1];
    const float* ew    = (const float*)d_in[2];
    const int*   batch = (const int*)  d_in[3];
    const float* W1    = (const float*)d_in[4];
    const float* b1    = (const float*)d_in[5];
    const float* W2    = (const float*)d_in[6];
    const float* b2    = (const float*)d_in[7];
    const float* Wc    = (const float*)d_in[8];
    const float* bc    = (const float*)d_in[9];
    float* out = (float*)d_out;

    const int* row = ei;
    const int* col = ei + N_EDGES;

    // workspace (~77.6 MB): recs | xlA | xlB | csr | rowptr | dis | bsum | boff | out_acc
    // H aliases csr (dead before bsort writes csr).
    int2*     recs   = (int2*)d_ws;                              // E int2 = 25.6 MB
    ushort_t* xlA    = (ushort_t*)(recs + N_EDGES);              // N*HID bf16
    ushort_t* xlB    = xlA + (size_t)N_NODES * HID;              // N*HID bf16
    float2*   csr    = (float2*)(xlB + (size_t)N_NODES * HID);   // E float2
    int*      rowptr = (int*)(csr + N_EDGES);                    // N_PAD
    float*    dis    = (float*)(rowptr + N_PAD);                 // N_PAD
    int*      bsum   = (int*)(dis + N_PAD);                      // 512
    int*      boff   = bsum + 512;                               // 512
    float*    out_acc= (float*)(boff + 512);                     // 256
    int*      H      = (int*)csr;                                // NB*NBLK ints = 401 KB

    hipMemsetAsync(out_acc, 0, N_GRAPHS * sizeof(float), stream);
    bhist_kernel    <<<NBLK, 256, 0, stream>>>(col, H);
    scan1_kernel    <<<NB,   256, 0, stream>>>(H, bsum);
    scan2_kernel    <<<1,    256, 0, stream>>>(bsum, boff);
    bscatter_kernel <<<NBLK, 256, 0, stream>>>(row, col, ew, H, boff, recs);
    degdis_kernel   <<<NB,   256, 0, stream>>>(recs, boff, dis);
    bsort_kernel    <<<NB,   256, 0, stream>>>(recs, boff, dis, csr, rowptr);
    gemm1_kernel    <<<N_NODES / 4, 256, 0, stream>>>(x, W1, xlA);
    gather_gemm2_kernel<<<N_NODES / 4, 256, 0, stream>>>(csr, rowptr, dis, xlA, W2, b1, xlB);
    gather_pool_kernel <<<N_NODES / 4, 256, 0, stream>>>(csr, rowptr, dis, xlB, b2, Wc,
                                                         batch, out_acc);
    final_out_kernel<<<1, 256, 0, stream>>>(out_acc, batch, bc, out);
}

// Round 10
// 486.840 us; speedup vs baseline: 1.6702x; 1.6702x over previous
//
#include <hip/hip_runtime.h>

#define N_NODES 100000
#define N_PAD   100352        // 392*256
#define N_EDGES 3200000
#define IN_DIM  128
#define HID     64
#define N_GRAPHS 256
#define NB      392           // buckets of 256 dest nodes each
#define NBLK    256           // hist/scatter blocks
#define EPB     (N_EDGES / NBLK)   // 12500

typedef unsigned short ushort_t;
typedef unsigned int   uint_t;

// bf16 helpers: storage-only compression of the gathered operand
__device__ __forceinline__ ushort_t f2bf(float v) {          // round-to-nearest-even
    uint_t b = __float_as_uint(v);
    b += 0x7fffu + ((b >> 16) & 1u);
    return (ushort_t)(b >> 16);
}
__device__ __forceinline__ void bf2f2(uint_t u, float& lo, float& hi) {
    lo = __uint_as_float(u << 16);
    hi = __uint_as_float(u & 0xffff0000u);
}
// 16B load -> 8 floats
__device__ __forceinline__ void ld_bf16x8(const ushort_t* p, float4& a, float4& b) {
    uint4 u = *(const uint4*)p;
    bf2f2(u.x, a.x, a.y); bf2f2(u.y, a.z, a.w);
    bf2f2(u.z, b.x, b.y); bf2f2(u.w, b.z, b.w);
}

// ---------- phase 1: per-block bucket histogram (LDS only, no global atomics) ----------
__global__ __launch_bounds__(256) void bhist_kernel(const int* __restrict__ col,
                                                    int* __restrict__ H) {
    __shared__ int h[NB];
    for (int i = threadIdx.x; i < NB; i += 256) h[i] = 0;
    __syncthreads();
    const int4* col4 = (const int4*)col;
    int base4 = blockIdx.x * (EPB / 4);
    for (int j = threadIdx.x; j < EPB / 4; j += 256) {
        int4 c = col4[base4 + j];
        atomicAdd(&h[c.x >> 8], 1);
        atomicAdd(&h[c.y >> 8], 1);
        atomicAdd(&h[c.z >> 8], 1);
        atomicAdd(&h[c.w >> 8], 1);
    }
    __syncthreads();
    for (int i = threadIdx.x; i < NB; i += 256) H[i * NBLK + blockIdx.x] = h[i];
}

// ---------- phase 2: exclusive scan of H (NB*NBLK, bucket-major) ----------
__global__ __launch_bounds__(256) void scan1_kernel(int* H, int* __restrict__ bsum) {
    __shared__ int s[256];
    int i = blockIdx.x * 256 + threadIdx.x;   // blockIdx.x == bucket (NBLK==256)
    int v = H[i];
    s[threadIdx.x] = v;
    __syncthreads();
    #pragma unroll
    for (int off = 1; off < 256; off <<= 1) {
        int t = (threadIdx.x >= off) ? s[threadIdx.x - off] : 0;
        __syncthreads();
        s[threadIdx.x] += t;
        __syncthreads();
    }
    H[i] = s[threadIdx.x] - v;                           // exclusive within bucket
    if (threadIdx.x == 255) bsum[blockIdx.x] = s[255];   // bucket total
}

__global__ __launch_bounds__(256) void scan2_kernel(const int* __restrict__ bsum,
                                                    int* __restrict__ boff) {
    __shared__ int s[256];
    __shared__ int carry;
    if (threadIdx.x == 0) carry = 0;
    __syncthreads();
    for (int c = 0; c < (NB + 255) / 256; ++c) {
        int i = c * 256 + threadIdx.x;
        int v = (i < NB) ? bsum[i] : 0;
        s[threadIdx.x] = v;
        __syncthreads();
        #pragma unroll
        for (int off = 1; off < 256; off <<= 1) {
            int t = (threadIdx.x >= off) ? s[threadIdx.x - off] : 0;
            __syncthreads();
            s[threadIdx.x] += t;
            __syncthreads();
        }
        if (i < NB) boff[i] = s[threadIdx.x] - v + carry;   // bucket start offsets
        __syncthreads();
        if (threadIdx.x == 0) carry += s[255];
        __syncthreads();
    }
}

// ---------- phase 3: scatter records to bucket-contiguous; cursors in LDS ----------
// rec = (row | local<<17, ew); local = col & 255 (8 bits), row < 2^17
__global__ __launch_bounds__(256) void bscatter_kernel(const int* __restrict__ row,
                                                       const int* __restrict__ col,
                                                       const float* __restrict__ ew,
                                                       const int* __restrict__ H,
                                                       const int* __restrict__ boff,
                                                       int2* __restrict__ recs) {
    __shared__ int cur[NB];
    for (int i = threadIdx.x; i < NB; i += 256)
        cur[i] = H[i * NBLK + blockIdx.x] + boff[i];      // fused scan3
    __syncthreads();
    const int4*   row4 = (const int4*)row;
    const int4*   col4 = (const int4*)col;
    const float4* ew4  = (const float4*)ew;
    int base4 = blockIdx.x * (EPB / 4);
    for (int j = threadIdx.x; j < EPB / 4; j += 256) {
        int4   r4 = row4[base4 + j];
        int4   c4 = col4[base4 + j];
        float4 w4 = ew4[base4 + j];
        int p0 = atomicAdd(&cur[c4.x >> 8], 1);
        recs[p0] = make_int2(r4.x | ((c4.x & 255) << 17), __float_as_int(w4.x));
        int p1 = atomicAdd(&cur[c4.y >> 8], 1);
        recs[p1] = make_int2(r4.y | ((c4.y & 255) << 17), __float_as_int(w4.y));
        int p2 = atomicAdd(&cur[c4.z >> 8], 1);
        recs[p2] = make_int2(r4.z | ((c4.z & 255) << 17), __float_as_int(w4.z));
        int p3 = atomicAdd(&cur[c4.w >> 8], 1);
        recs[p3] = make_int2(r4.w | ((c4.w & 255) << 17), __float_as_int(w4.w));
    }
}

// ---------- phase 3.5: deg/dis per bucket from recs (LDS accumulation) ----------
__global__ __launch_bounds__(256) void degdis_kernel(const int2* __restrict__ recs,
                                                     const int* __restrict__ boff,
                                                     float* __restrict__ dis) {
    __shared__ float degf[256];
    int b = blockIdx.x, tid = threadIdx.x;
    degf[tid] = 0.f;
    __syncthreads();
    int s = boff[b], e = (b + 1 < NB) ? boff[b + 1] : N_EDGES;
    for (int j = s + tid; j < e; j += 256) {
        int2 r = recs[j];
        atomicAdd(&degf[(r.x >> 17) & 255], __int_as_float(r.y));
    }
    __syncthreads();
    dis[b * 256 + tid] = 1.0f / sqrtf(fmaxf(1.0f + degf[tid], 1e-30f));
}

// ---------- phase 4: per-bucket counting sort -> per-node CSR; FULL weight folded ----
// csr[pos] = (row, dis[row] * ew * dis[col])
__global__ __launch_bounds__(256) void bsort_kernel(const int2* __restrict__ recs,
                                                    const int* __restrict__ boff,
                                                    const float* __restrict__ dis,
                                                    float2* __restrict__ csr,
                                                    int* __restrict__ rowptr) {
    __shared__ int   cnt[256];
    __shared__ int   cur[256];
    __shared__ float sdis[256];
    __shared__ int   sscan[256];
    int b = blockIdx.x, tid = threadIdx.x;
    cnt[tid] = 0;
    sdis[tid] = dis[b * 256 + tid];
    __syncthreads();
    int s = boff[b], e = (b + 1 < NB) ? boff[b + 1] : N_EDGES;
    for (int j = s + tid; j < e; j += 256) {
        int2 r = recs[j];
        atomicAdd(&cnt[(r.x >> 17) & 255], 1);
    }
    __syncthreads();
    int c = cnt[tid];
    sscan[tid] = c;
    __syncthreads();
    #pragma unroll
    for (int off = 1; off < 256; off <<= 1) {
        int t = (tid >= off) ? sscan[tid - off] : 0;
        __syncthreads();
        sscan[tid] += t;
        __syncthreads();
    }
    int excl = sscan[tid] - c;
    cur[tid] = excl;
    rowptr[b * 256 + tid] = s + excl;    // trailing zero-cnt nodes give rowptr[N]=E
    __syncthreads();
    for (int j = s + tid; j < e; j += 256) {
        int2 r = recs[j];
        int cl = (r.x >> 17) & 255;
        int rr = r.x & 0x1FFFF;
        int pos = s + atomicAdd(&cur[cl], 1);
        csr[pos] = make_float2(__int_as_float(rr),
                               dis[rr] * __int_as_float(r.y) * sdis[cl]);
    }
}

// ---------- layer 1 GEMM: xl = x @ W1 (bf16 output) ----------
__global__ __launch_bounds__(256) void gemm1_kernel(const float* __restrict__ x,
                                                    const float* __restrict__ W1,
                                                    ushort_t* __restrict__ xl) {
    __shared__ float sW[IN_DIM * HID];   // 32 KB
    __shared__ float sx[4][IN_DIM];
    int tid = threadIdx.x;
    const float4* W4  = (const float4*)W1;
    float4*       sW4 = (float4*)sW;
    #pragma unroll
    for (int i = 0; i < 8; ++i) sW4[tid + 256 * i] = W4[tid + 256 * i];
    int r0 = blockIdx.x * 4;
    const float4* x4  = (const float4*)(x + (size_t)r0 * IN_DIM);
    float4*       sx4 = (float4*)&sx[0][0];
    if (tid < 128) sx4[tid] = x4[tid];
    __syncthreads();
    int lr = tid >> 6, c = tid & 63;
    float acc = 0.f;
    #pragma unroll 8
    for (int k = 0; k < IN_DIM; ++k) acc += sx[lr][k] * sW[k * HID + c];
    xl[(size_t)(r0 + lr) * HID + c] = f2bf(acc);
}

// ---------- gather core: 8-lane groups, 16B loads, 4 edges in flight/group ----------
// lanes 0..7 hold the final 64-channel row (8 channels each) after reduction
__device__ __forceinline__ void gather_row(const float2* __restrict__ csr,
                                           const ushort_t* __restrict__ xl,
                                           int base, int end, int n, float d2,
                                           int g, int c0,
                                           float4& a0, float4& a1) {
    a0 = make_float4(0.f, 0.f, 0.f, 0.f);
    a1 = make_float4(0.f, 0.f, 0.f, 0.f);
    if (g == 0) {
        float4 s0, s1;
        ld_bf16x8(xl + (size_t)n * HID + c0, s0, s1);
        a0.x = s0.x * d2; a0.y = s0.y * d2; a0.z = s0.z * d2; a0.w = s0.w * d2;
        a1.x = s1.x * d2; a1.y = s1.y * d2; a1.z = s1.z * d2; a1.w = s1.w * d2;
    }
    int j = base + g;
    for (; j + 24 < end; j += 32) {                      // 4 edges in flight
        float2 e0 = csr[j];
        float2 e1 = csr[j + 8];
        float2 e2 = csr[j + 16];
        float2 e3 = csr[j + 24];
        int r0_ = __float_as_int(e0.x), r1_ = __float_as_int(e1.x);
        int r2_ = __float_as_int(e2.x), r3_ = __float_as_int(e3.x);
        float4 xa0, xa1, xb0, xb1, xc0, xc1, xd0, xd1;
        ld_bf16x8(xl + (size_t)r0_ * HID + c0, xa0, xa1);
        ld_bf16x8(xl + (size_t)r1_ * HID + c0, xb0, xb1);
        ld_bf16x8(xl + (size_t)r2_ * HID + c0, xc0, xc1);
        ld_bf16x8(xl + (size_t)r3_ * HID + c0, xd0, xd1);
        a0.x += xa0.x * e0.y + xb0.x * e1.y + xc0.x * e2.y + xd0.x * e3.y;
        a0.y += xa0.y * e0.y + xb0.y * e1.y + xc0.y * e2.y + xd0.y * e3.y;
        a0.z += xa0.z * e0.y + xb0.z * e1.y + xc0.z * e2.y + xd0.z * e3.y;
        a0.w += xa0.w * e0.y + xb0.w * e1.y + xc0.w * e2.y + xd0.w * e3.y;
        a1.x += xa1.x * e0.y + xb1.x * e1.y + xc1.x * e2.y + xd1.x * e3.y;
        a1.y += xa1.y * e0.y + xb1.y * e1.y + xc1.y * e2.y + xd1.y * e3.y;
        a1.z += xa1.z * e0.y + xb1.z * e1.y + xc1.z * e2.y + xd1.z * e3.y;
        a1.w += xa1.w * e0.y + xb1.w * e1.y + xc1.w * e2.y + xd1.w * e3.y;
    }
    for (; j < end; j += 8) {
        float2 e0 = csr[j];
        int ra = __float_as_int(e0.x);
        float w0 = e0.y;
        float4 xa0, xa1;
        ld_bf16x8(xl + (size_t)ra * HID + c0, xa0, xa1);
        a0.x += xa0.x * w0; a0.y += xa0.y * w0; a0.z += xa0.z * w0; a0.w += xa0.w * w0;
        a1.x += xa1.x * w0; a1.y += xa1.y * w0; a1.z += xa1.z * w0; a1.w += xa1.w * w0;
    }
    #pragma unroll
    for (int o = 32; o >= 8; o >>= 1) {
        a0.x += __shfl_down(a0.x, o, 64); a0.y += __shfl_down(a0.y, o, 64);
        a0.z += __shfl_down(a0.z, o, 64); a0.w += __shfl_down(a0.w, o, 64);
        a1.x += __shfl_down(a1.x, o, 64); a1.y += __shfl_down(a1.y, o, 64);
        a1.z += __shfl_down(a1.z, o, 64); a1.w += __shfl_down(a1.w, o, 64);
    }
}

// ---------- fused gather1 + gemm2: xl2 = relu(gather(xl1) + b1) @ W2 (bf16 out) ----------
__global__ __launch_bounds__(256) void gather_gemm2_kernel(
        const float2* __restrict__ csr, const int* __restrict__ rowptr,
        const float* __restrict__ dis, const ushort_t* __restrict__ xl,
        const float* __restrict__ W2, const float* __restrict__ b1,
        ushort_t* __restrict__ xl2) {
    __shared__ float sW[HID * HID];   // 16 KB
    __shared__ float sh[4][HID];
    __shared__ float sb1[HID];
    int tid = threadIdx.x;
    const float4* W4  = (const float4*)W2;
    float4*       sW4 = (float4*)sW;
    #pragma unroll
    for (int i = 0; i < 4; ++i) sW4[tid + 256 * i] = W4[tid + 256 * i];
    if (tid < HID) sb1[tid] = b1[tid];

    int r0   = blockIdx.x * 4;
    int wv   = tid >> 6;
    int n    = r0 + wv;
    int lane = tid & 63;
    int g    = lane >> 3;
    int c0   = (lane & 7) << 3;
    int base = rowptr[n], end = rowptr[n + 1];
    float d  = dis[n];
    float4 a0, a1;
    gather_row(csr, xl, base, end, n, d * d, g, c0, a0, a1);
    if (lane < 8) {
        *(float4*)(&sh[wv][c0])     = a0;
        *(float4*)(&sh[wv][c0 + 4]) = a1;
    }
    __syncthreads();                                    // sW, sb1, sh all visible
    int lr = wv, cc = lane;
    float hv = fmaxf(sh[lr][cc] + sb1[cc], 0.f);        // relu(agg1 + b1)
    __syncthreads();
    sh[lr][cc] = hv;
    __syncthreads();
    float acc2 = 0.f;
    #pragma unroll 8
    for (int k = 0; k < HID; ++k) acc2 += sh[lr][k] * sW[k * HID + cc];
    xl2[(size_t)(r0 + lr) * HID + cc] = f2bf(acc2);
}

// ---------- fused gather2 + pool partial: sval[n] = relu(agg2[n]+b2) . Wc ----------
// coalesced scalar store per node; NO atomics (256-slot atomic target serializes at L2)
__global__ __launch_bounds__(256) void gather_pool_kernel(
        const float2* __restrict__ csr, const int* __restrict__ rowptr,
        const float* __restrict__ dis, const ushort_t* __restrict__ xl,
        const float* __restrict__ b2, const float* __restrict__ Wc,
        float* __restrict__ sval) {
    int tid  = threadIdx.x;
    int n    = (blockIdx.x * 256 + tid) >> 6;           // grid 25000 exact
    int lane = tid & 63;
    int g    = lane >> 3;
    int c0   = (lane & 7) << 3;
    int base = rowptr[n], end = rowptr[n + 1];
    float d  = dis[n];
    float4 a0, a1;
    gather_row(csr, xl, base, end, n, d * d, g, c0, a0, a1);
    if (lane < 8) {
        float4 bb0 = *(const float4*)(b2 + c0);
        float4 bb1 = *(const float4*)(b2 + c0 + 4);
        float4 wc0 = *(const float4*)(Wc + c0);
        float4 wc1 = *(const float4*)(Wc + c0 + 4);
        float s = fmaxf(a0.x + bb0.x, 0.f) * wc0.x + fmaxf(a0.y + bb0.y, 0.f) * wc0.y
                + fmaxf(a0.z + bb0.z, 0.f) * wc0.z + fmaxf(a0.w + bb0.w, 0.f) * wc0.w
                + fmaxf(a1.x + bb1.x, 0.f) * wc1.x + fmaxf(a1.y + bb1.y, 0.f) * wc1.y
                + fmaxf(a1.z + bb1.z, 0.f) * wc1.z + fmaxf(a1.w + bb1.w, 0.f) * wc1.w;
        s += __shfl_down(s, 4, 64);
        s += __shfl_down(s, 2, 64);
        s += __shfl_down(s, 1, 64);
        if (lane == 0) sval[n] = s;
    }
}

// ---------- final: out[g] = mean(sval over graph range) + bc ----------
__global__ __launch_bounds__(256) void final_out_kernel(const float* __restrict__ sval,
                                                        const int* __restrict__ batch,
                                                        const float* __restrict__ bc,
                                                        float* __restrict__ out) {
    __shared__ float s[256];
    int g = blockIdx.x;   // grid N_GRAPHS
    int lo = 0, hi = N_NODES;
    while (lo < hi) { int m = (lo + hi) >> 1; if (batch[m] < g) lo = m + 1; else hi = m; }
    int start = lo;
    hi = N_NODES;
    while (lo < hi) { int m = (lo + hi) >> 1; if (batch[m] < g + 1) lo = m + 1; else hi = m; }
    int end = lo;
    float acc = 0.f;
    for (int i = start + threadIdx.x; i < end; i += 256) acc += sval[i];
    s[threadIdx.x] = acc;
    __syncthreads();
    #pragma unroll
    for (int off = 128; off > 0; off >>= 1) {
        if (threadIdx.x < off) s[threadIdx.x] += s[threadIdx.x + off];
        __syncthreads();
    }
    if (threadIdx.x == 0)
        out[g] = s[0] / fmaxf((float)(end - start), 1.0f) + bc[0];
}

extern "C" void kernel_launch(void* const* d_in, const int* in_sizes, int n_in,
                              void* d_out, int out_size, void* d_ws, size_t ws_size,
                              hipStream_t stream) {
    const float* x     = (const float*)d_in[0];
    const int*   ei    = (const int*)  d_in[1];
    const float* ew    = (const float*)d_in[2];
    const int*   batch = (const int*)  d_in[3];
    const float* W1    = (const float*)d_in[4];
    const float* b1    = (const float*)d_in[5];
    const float* W2    = (const float*)d_in[6];
    const float* b2    = (const float*)d_in[7];
    const float* Wc    = (const float*)d_in[8];
    const float* bc    = (const float*)d_in[9];
    float* out = (float*)d_out;

    const int* row = ei;
    const int* col = ei + N_EDGES;

    // workspace (~78 MB): recs | xlA | xlB | csr | rowptr | dis | bsum | boff | sval
    // H aliases csr (dead before bsort writes csr).
    int2*     recs   = (int2*)d_ws;                              // E int2 = 25.6 MB
    ushort_t* xlA    = (ushort_t*)(recs + N_EDGES);              // N*HID bf16
    ushort_t* xlB    = xlA + (size_t)N_NODES * HID;              // N*HID bf16
    float2*   csr    = (float2*)(xlB + (size_t)N_NODES * HID);   // E float2
    int*      rowptr = (int*)(csr + N_EDGES);                    // N_PAD
    float*    dis    = (float*)(rowptr + N_PAD);                 // N_PAD
    int*      bsum   = (int*)(dis + N_PAD);                      // 512
    int*      boff   = bsum + 512;                               // 512
    float*    sval   = (float*)(boff + 512);                     // N_PAD
    int*      H      = (int*)csr;                                // NB*NBLK ints = 401 KB

    bhist_kernel    <<<NBLK, 256, 0, stream>>>(col, H);
    scan1_kernel    <<<NB,   256, 0, stream>>>(H, bsum);
    scan2_kernel    <<<1,    256, 0, stream>>>(bsum, boff);
    bscatter_kernel <<<NBLK, 256, 0, stream>>>(row, col, ew, H, boff, recs);
    degdis_kernel   <<<NB,   256, 0, stream>>>(recs, boff, dis);
    bsort_kernel    <<<NB,   256, 0, stream>>>(recs, boff, dis, csr, rowptr);
    gemm1_kernel    <<<N_NODES / 4, 256, 0, stream>>>(x, W1, xlA);
    gather_gemm2_kernel<<<N_NODES / 4, 256, 0, stream>>>(csr, rowptr, dis, xlA, W2, b1, xlB);
    gather_pool_kernel <<<N_NODES / 4, 256, 0, stream>>>(csr, rowptr, dis, xlB, b2, Wc, sval);
    final_out_kernel<<<N_GRAPHS, 256, 0, stream>>>(sval, batch, bc, out);
}

// Round 11
// 471.080 us; speedup vs baseline: 1.7261x; 1.0335x over previous
//
#include <hip/hip_runtime.h>

#define N_NODES 100000
#define N_PAD   100352        // 392*256
#define N_EDGES 3200000
#define IN_DIM  128
#define HID     64
#define N_GRAPHS 256
#define NB      392           // buckets of 256 dest nodes each
#define NBLK    256           // hist/scatter blocks
#define EPB     (N_EDGES / NBLK)   // 12500

typedef unsigned short ushort_t;
typedef unsigned int   uint_t;

// bf16 helpers: storage-only compression of the gathered operand
__device__ __forceinline__ ushort_t f2bf(float v) {          // round-to-nearest-even
    uint_t b = __float_as_uint(v);
    b += 0x7fffu + ((b >> 16) & 1u);
    return (ushort_t)(b >> 16);
}
__device__ __forceinline__ void bf2f2(uint_t u, float& lo, float& hi) {
    lo = __uint_as_float(u << 16);
    hi = __uint_as_float(u & 0xffff0000u);
}
// 16B load -> 8 floats
__device__ __forceinline__ void ld_bf16x8(const ushort_t* p, float4& a, float4& b) {
    uint4 u = *(const uint4*)p;
    bf2f2(u.x, a.x, a.y); bf2f2(u.y, a.z, a.w);
    bf2f2(u.z, b.x, b.y); bf2f2(u.w, b.z, b.w);
}

// ---------- phase 1: per-block bucket histogram (LDS only, no global atomics) ----------
__global__ __launch_bounds__(256) void bhist_kernel(const int* __restrict__ col,
                                                    int* __restrict__ H) {
    __shared__ int h[NB];
    for (int i = threadIdx.x; i < NB; i += 256) h[i] = 0;
    __syncthreads();
    const int4* col4 = (const int4*)col;
    int base4 = blockIdx.x * (EPB / 4);
    for (int j = threadIdx.x; j < EPB / 4; j += 256) {
        int4 c = col4[base4 + j];
        atomicAdd(&h[c.x >> 8], 1);
        atomicAdd(&h[c.y >> 8], 1);
        atomicAdd(&h[c.z >> 8], 1);
        atomicAdd(&h[c.w >> 8], 1);
    }
    __syncthreads();
    for (int i = threadIdx.x; i < NB; i += 256) H[i * NBLK + blockIdx.x] = h[i];
}

// ---------- phase 2: exclusive scan of H (NB*NBLK, bucket-major) ----------
__global__ __launch_bounds__(256) void scan1_kernel(int* H, int* __restrict__ bsum) {
    __shared__ int s[256];
    int i = blockIdx.x * 256 + threadIdx.x;   // blockIdx.x == bucket (NBLK==256)
    int v = H[i];
    s[threadIdx.x] = v;
    __syncthreads();
    #pragma unroll
    for (int off = 1; off < 256; off <<= 1) {
        int t = (threadIdx.x >= off) ? s[threadIdx.x - off] : 0;
        __syncthreads();
        s[threadIdx.x] += t;
        __syncthreads();
    }
    H[i] = s[threadIdx.x] - v;                           // exclusive within bucket
    if (threadIdx.x == 255) bsum[blockIdx.x] = s[255];   // bucket total
}

// ---------- phase 3: scatter records; bucket-offset scan (old scan2) folded in ----------
// rec = (row | local<<17, ew); local = col & 255 (8 bits), row < 2^17
__global__ __launch_bounds__(256) void bscatter_kernel(const int* __restrict__ row,
                                                       const int* __restrict__ col,
                                                       const float* __restrict__ ew,
                                                       const int* __restrict__ H,
                                                       const int* __restrict__ bsum,
                                                       int* __restrict__ boff,
                                                       int2* __restrict__ recs) {
    __shared__ int cur[NB];
    __shared__ int tboff[NB];
    __shared__ int s[256];
    __shared__ int carry;
    int tid = threadIdx.x;
    if (tid == 0) carry = 0;
    __syncthreads();
    // local exclusive scan of bsum[0..NB) -> tboff (every block does it; ~1 us)
    for (int c = 0; c < (NB + 255) / 256; ++c) {
        int i = c * 256 + tid;
        int v = (i < NB) ? bsum[i] : 0;
        s[tid] = v;
        __syncthreads();
        #pragma unroll
        for (int off = 1; off < 256; off <<= 1) {
            int t = (tid >= off) ? s[tid - off] : 0;
            __syncthreads();
            s[tid] += t;
            __syncthreads();
        }
        if (i < NB) tboff[i] = s[tid] - v + carry;
        __syncthreads();
        if (tid == 0) carry += s[255];
        __syncthreads();
    }
    for (int i = tid; i < NB; i += 256)
        cur[i] = H[i * NBLK + blockIdx.x] + tboff[i];
    if (blockIdx.x == 0)                      // publish boff for later kernels
        for (int i = tid; i < NB; i += 256) boff[i] = tboff[i];
    __syncthreads();
    const int4*   row4 = (const int4*)row;
    const int4*   col4 = (const int4*)col;
    const float4* ew4  = (const float4*)ew;
    int base4 = blockIdx.x * (EPB / 4);
    for (int j = tid; j < EPB / 4; j += 256) {
        int4   r4 = row4[base4 + j];
        int4   c4 = col4[base4 + j];
        float4 w4 = ew4[base4 + j];
        int p0 = atomicAdd(&cur[c4.x >> 8], 1);
        recs[p0] = make_int2(r4.x | ((c4.x & 255) << 17), __float_as_int(w4.x));
        int p1 = atomicAdd(&cur[c4.y >> 8], 1);
        recs[p1] = make_int2(r4.y | ((c4.y & 255) << 17), __float_as_int(w4.y));
        int p2 = atomicAdd(&cur[c4.z >> 8], 1);
        recs[p2] = make_int2(r4.z | ((c4.z & 255) << 17), __float_as_int(w4.z));
        int p3 = atomicAdd(&cur[c4.w >> 8], 1);
        recs[p3] = make_int2(r4.w | ((c4.w & 255) << 17), __float_as_int(w4.w));
    }
}

// ---------- phase 3.5: deg/dis per bucket from recs (LDS accumulation) ----------
__global__ __launch_bounds__(256) void degdis_kernel(const int2* __restrict__ recs,
                                                     const int* __restrict__ boff,
                                                     float* __restrict__ dis) {
    __shared__ float degf[256];
    int b = blockIdx.x, tid = threadIdx.x;
    degf[tid] = 0.f;
    __syncthreads();
    int s = boff[b], e = (b + 1 < NB) ? boff[b + 1] : N_EDGES;
    for (int j = s + tid; j < e; j += 256) {
        int2 r = recs[j];
        atomicAdd(&degf[(r.x >> 17) & 255], __int_as_float(r.y));
    }
    __syncthreads();
    dis[b * 256 + tid] = 1.0f / sqrtf(fmaxf(1.0f + degf[tid], 1e-30f));
}

// ---------- phase 4: per-bucket counting sort -> per-node CSR; FULL weight folded ----
// csr[pos] = (row, dis[row] * ew * dis[col])
__global__ __launch_bounds__(256) void bsort_kernel(const int2* __restrict__ recs,
                                                    const int* __restrict__ boff,
                                                    const float* __restrict__ dis,
                                                    float2* __restrict__ csr,
                                                    int* __restrict__ rowptr) {
    __shared__ int   cnt[256];
    __shared__ int   cur[256];
    __shared__ float sdis[256];
    __shared__ int   sscan[256];
    int b = blockIdx.x, tid = threadIdx.x;
    cnt[tid] = 0;
    sdis[tid] = dis[b * 256 + tid];
    __syncthreads();
    int s = boff[b], e = (b + 1 < NB) ? boff[b + 1] : N_EDGES;
    for (int j = s + tid; j < e; j += 256) {
        int2 r = recs[j];
        atomicAdd(&cnt[(r.x >> 17) & 255], 1);
    }
    __syncthreads();
    int c = cnt[tid];
    sscan[tid] = c;
    __syncthreads();
    #pragma unroll
    for (int off = 1; off < 256; off <<= 1) {
        int t = (tid >= off) ? sscan[tid - off] : 0;
        __syncthreads();
        sscan[tid] += t;
        __syncthreads();
    }
    int excl = sscan[tid] - c;
    cur[tid] = excl;
    rowptr[b * 256 + tid] = s + excl;    // trailing zero-cnt nodes give rowptr[N]=E
    __syncthreads();
    for (int j = s + tid; j < e; j += 256) {
        int2 r = recs[j];
        int cl = (r.x >> 17) & 255;
        int rr = r.x & 0x1FFFF;
        int pos = s + atomicAdd(&cur[cl], 1);
        csr[pos] = make_float2(__int_as_float(rr),
                               dis[rr] * __int_as_float(r.y) * sdis[cl]);
    }
}

// ---------- layer 1 GEMM: xl = x @ W1 (bf16 output), 8 rows/block ----------
__global__ __launch_bounds__(256) void gemm1_kernel(const float* __restrict__ x,
                                                    const float* __restrict__ W1,
                                                    ushort_t* __restrict__ xl) {
    __shared__ float sW[IN_DIM * HID];   // 32 KB
    __shared__ float sx[8][IN_DIM];      // 4 KB
    int tid = threadIdx.x;
    const float4* W4  = (const float4*)W1;
    float4*       sW4 = (float4*)sW;
    #pragma unroll
    for (int i = 0; i < 8; ++i) sW4[tid + 256 * i] = W4[tid + 256 * i];
    int r0 = blockIdx.x * 8;             // grid 12500 exact
    const float4* x4  = (const float4*)(x + (size_t)r0 * IN_DIM);
    float4*       sx4 = (float4*)&sx[0][0];
    sx4[tid] = x4[tid];                  // 256 float4 = 8 rows x 128
    __syncthreads();
    int c = tid & 63;
    #pragma unroll
    for (int rep = 0; rep < 2; ++rep) {
        int lr = (tid >> 6) * 2 + rep;   // 0..7
        float acc = 0.f;
        #pragma unroll 8
        for (int k = 0; k < IN_DIM; ++k) acc += sx[lr][k] * sW[k * HID + c];
        xl[(size_t)(r0 + lr) * HID + c] = f2bf(acc);
    }
}

// ---------- gather core: 8-lane groups, 16B loads, 4 edges in flight/group ----------
// lanes 0..7 hold the final 64-channel row (8 channels each) after reduction
__device__ __forceinline__ void gather_row(const float2* __restrict__ csr,
                                           const ushort_t* __restrict__ xl,
                                           int base, int end, int n, float d2,
                                           int g, int c0,
                                           float4& a0, float4& a1) {
    a0 = make_float4(0.f, 0.f, 0.f, 0.f);
    a1 = make_float4(0.f, 0.f, 0.f, 0.f);
    if (g == 0) {
        float4 s0, s1;
        ld_bf16x8(xl + (size_t)n * HID + c0, s0, s1);
        a0.x = s0.x * d2; a0.y = s0.y * d2; a0.z = s0.z * d2; a0.w = s0.w * d2;
        a1.x = s1.x * d2; a1.y = s1.y * d2; a1.z = s1.z * d2; a1.w = s1.w * d2;
    }
    int j = base + g;
    for (; j + 24 < end; j += 32) {                      // 4 edges in flight
        float2 e0 = csr[j];
        float2 e1 = csr[j + 8];
        float2 e2 = csr[j + 16];
        float2 e3 = csr[j + 24];
        int r0_ = __float_as_int(e0.x), r1_ = __float_as_int(e1.x);
        int r2_ = __float_as_int(e2.x), r3_ = __float_as_int(e3.x);
        float4 xa0, xa1, xb0, xb1, xc0, xc1, xd0, xd1;
        ld_bf16x8(xl + (size_t)r0_ * HID + c0, xa0, xa1);
        ld_bf16x8(xl + (size_t)r1_ * HID + c0, xb0, xb1);
        ld_bf16x8(xl + (size_t)r2_ * HID + c0, xc0, xc1);
        ld_bf16x8(xl + (size_t)r3_ * HID + c0, xd0, xd1);
        a0.x += xa0.x * e0.y + xb0.x * e1.y + xc0.x * e2.y + xd0.x * e3.y;
        a0.y += xa0.y * e0.y + xb0.y * e1.y + xc0.y * e2.y + xd0.y * e3.y;
        a0.z += xa0.z * e0.y + xb0.z * e1.y + xc0.z * e2.y + xd0.z * e3.y;
        a0.w += xa0.w * e0.y + xb0.w * e1.y + xc0.w * e2.y + xd0.w * e3.y;
        a1.x += xa1.x * e0.y + xb1.x * e1.y + xc1.x * e2.y + xd1.x * e3.y;
        a1.y += xa1.y * e0.y + xb1.y * e1.y + xc1.y * e2.y + xd1.y * e3.y;
        a1.z += xa1.z * e0.y + xb1.z * e1.y + xc1.z * e2.y + xd1.z * e3.y;
        a1.w += xa1.w * e0.y + xb1.w * e1.y + xc1.w * e2.y + xd1.w * e3.y;
    }
    for (; j < end; j += 8) {
        float2 e0 = csr[j];
        int ra = __float_as_int(e0.x);
        float w0 = e0.y;
        float4 xa0, xa1;
        ld_bf16x8(xl + (size_t)ra * HID + c0, xa0, xa1);
        a0.x += xa0.x * w0; a0.y += xa0.y * w0; a0.z += xa0.z * w0; a0.w += xa0.w * w0;
        a1.x += xa1.x * w0; a1.y += xa1.y * w0; a1.z += xa1.z * w0; a1.w += xa1.w * w0;
    }
    #pragma unroll
    for (int o = 32; o >= 8; o >>= 1) {
        a0.x += __shfl_down(a0.x, o, 64); a0.y += __shfl_down(a0.y, o, 64);
        a0.z += __shfl_down(a0.z, o, 64); a0.w += __shfl_down(a0.w, o, 64);
        a1.x += __shfl_down(a1.x, o, 64); a1.y += __shfl_down(a1.y, o, 64);
        a1.z += __shfl_down(a1.z, o, 64); a1.w += __shfl_down(a1.w, o, 64);
    }
}

// ---------- fused gather1 + gemm2: xl2 = relu(gather(xl1) + b1) @ W2 (bf16 out) ----------
__global__ __launch_bounds__(256) void gather_gemm2_kernel(
        const float2* __restrict__ csr, const int* __restrict__ rowptr,
        const float* __restrict__ dis, const ushort_t* __restrict__ xl,
        const float* __restrict__ W2, const float* __restrict__ b1,
        ushort_t* __restrict__ xl2) {
    __shared__ float sW[HID * HID];   // 16 KB
    __shared__ float sh[4][HID];
    __shared__ float sb1[HID];
    int tid = threadIdx.x;
    const float4* W4  = (const float4*)W2;
    float4*       sW4 = (float4*)sW;
    #pragma unroll
    for (int i = 0; i < 4; ++i) sW4[tid + 256 * i] = W4[tid + 256 * i];
    if (tid < HID) sb1[tid] = b1[tid];

    int r0   = blockIdx.x * 4;
    int wv   = tid >> 6;
    int n    = r0 + wv;
    int lane = tid & 63;
    int g    = lane >> 3;
    int c0   = (lane & 7) << 3;
    int base = rowptr[n], end = rowptr[n + 1];
    float d  = dis[n];
    float4 a0, a1;
    gather_row(csr, xl, base, end, n, d * d, g, c0, a0, a1);
    if (lane < 8) {
        *(float4*)(&sh[wv][c0])     = a0;
        *(float4*)(&sh[wv][c0 + 4]) = a1;
    }
    __syncthreads();                                    // sW, sb1, sh all visible
    int lr = wv, cc = lane;
    float hv = fmaxf(sh[lr][cc] + sb1[cc], 0.f);        // relu(agg1 + b1)
    __syncthreads();
    sh[lr][cc] = hv;
    __syncthreads();
    float acc2 = 0.f;
    #pragma unroll 8
    for (int k = 0; k < HID; ++k) acc2 += sh[lr][k] * sW[k * HID + cc];
    xl2[(size_t)(r0 + lr) * HID + cc] = f2bf(acc2);
}

// ---------- fused gather2 + pool partial: sval[n] = relu(agg2[n]+b2) . Wc ----------
// coalesced scalar store per node; NO atomics (256-slot atomic target serializes at L2)
__global__ __launch_bounds__(256) void gather_pool_kernel(
        const float2* __restrict__ csr, const int* __restrict__ rowptr,
        const float* __restrict__ dis, const ushort_t* __restrict__ xl,
        const float* __restrict__ b2, const float* __restrict__ Wc,
        float* __restrict__ sval) {
    int tid  = threadIdx.x;
    int n    = (blockIdx.x * 256 + tid) >> 6;           // grid 25000 exact
    int lane = tid & 63;
    int g    = lane >> 3;
    int c0   = (lane & 7) << 3;
    int base = rowptr[n], end = rowptr[n + 1];
    float d  = dis[n];
    float4 a0, a1;
    gather_row(csr, xl, base, end, n, d * d, g, c0, a0, a1);
    if (lane < 8) {
        float4 bb0 = *(const float4*)(b2 + c0);
        float4 bb1 = *(const float4*)(b2 + c0 + 4);
        float4 wc0 = *(const float4*)(Wc + c0);
        float4 wc1 = *(const float4*)(Wc + c0 + 4);
        float s = fmaxf(a0.x + bb0.x, 0.f) * wc0.x + fmaxf(a0.y + bb0.y, 0.f) * wc0.y
                + fmaxf(a0.z + bb0.z, 0.f) * wc0.z + fmaxf(a0.w + bb0.w, 0.f) * wc0.w
                + fmaxf(a1.x + bb1.x, 0.f) * wc1.x + fmaxf(a1.y + bb1.y, 0.f) * wc1.y
                + fmaxf(a1.z + bb1.z, 0.f) * wc1.z + fmaxf(a1.w + bb1.w, 0.f) * wc1.w;
        s += __shfl_down(s, 4, 64);
        s += __shfl_down(s, 2, 64);
        s += __shfl_down(s, 1, 64);
        if (lane == 0) sval[n] = s;
    }
}

// ---------- final: out[g] = mean(sval over graph range) + bc ----------
__global__ __launch_bounds__(256) void final_out_kernel(const float* __restrict__ sval,
                                                        const int* __restrict__ batch,
                                                        const float* __restrict__ bc,
                                                        float* __restrict__ out) {
    __shared__ float s[256];
    int g = blockIdx.x;   // grid N_GRAPHS
    int lo = 0, hi = N_NODES;
    while (lo < hi) { int m = (lo + hi) >> 1; if (batch[m] < g) lo = m + 1; else hi = m; }
    int start = lo;
    hi = N_NODES;
    while (lo < hi) { int m = (lo + hi) >> 1; if (batch[m] < g + 1) lo = m + 1; else hi = m; }
    int end = lo;
    float acc = 0.f;
    for (int i = start + threadIdx.x; i < end; i += 256) acc += sval[i];
    s[threadIdx.x] = acc;
    __syncthreads();
    #pragma unroll
    for (int off = 128; off > 0; off >>= 1) {
        if (threadIdx.x < off) s[threadIdx.x] += s[threadIdx.x + off];
        __syncthreads();
    }
    if (threadIdx.x == 0)
        out[g] = s[0] / fmaxf((float)(end - start), 1.0f) + bc[0];
}

extern "C" void kernel_launch(void* const* d_in, const int* in_sizes, int n_in,
                              void* d_out, int out_size, void* d_ws, size_t ws_size,
                              hipStream_t stream) {
    const float* x     = (const float*)d_in[0];
    const int*   ei    = (const int*)  d_in[1];
    const float* ew    = (const float*)d_in[2];
    const int*   batch = (const int*)  d_in[3];
    const float* W1    = (const float*)d_in[4];
    const float* b1    = (const float*)d_in[5];
    const float* W2    = (const float*)d_in[6];
    const float* b2    = (const float*)d_in[7];
    const float* Wc    = (const float*)d_in[8];
    const float* bc    = (const float*)d_in[9];
    float* out = (float*)d_out;

    const int* row = ei;
    const int* col = ei + N_EDGES;

    // workspace (~78 MB): recs | xlA | xlB | csr | rowptr | dis | bsum | boff | sval
    // H aliases csr (dead before bsort writes csr).
    int2*     recs   = (int2*)d_ws;                              // E int2 = 25.6 MB
    ushort_t* xlA    = (ushort_t*)(recs + N_EDGES);              // N*HID bf16
    ushort_t* xlB    = xlA + (size_t)N_NODES * HID;              // N*HID bf16
    float2*   csr    = (float2*)(xlB + (size_t)N_NODES * HID);   // E float2
    int*      rowptr = (int*)(csr + N_EDGES);                    // N_PAD
    float*    dis    = (float*)(rowptr + N_PAD);                 // N_PAD
    int*      bsum   = (int*)(dis + N_PAD);                      // 512
    int*      boff   = bsum + 512;                               // 512
    float*    sval   = (float*)(boff + 512);                     // N_PAD
    int*      H      = (int*)csr;                                // NB*NBLK ints = 401 KB

    bhist_kernel    <<<NBLK, 256, 0, stream>>>(col, H);
    scan1_kernel    <<<NB,   256, 0, stream>>>(H, bsum);
    bscatter_kernel <<<NBLK, 256, 0, stream>>>(row, col, ew, H, bsum, boff, recs);
    degdis_kernel   <<<NB,   256, 0, stream>>>(recs, boff, dis);
    bsort_kernel    <<<NB,   256, 0, stream>>>(recs, boff, dis, csr, rowptr);
    gemm1_kernel    <<<N_NODES / 8, 256, 0, stream>>>(x, W1, xlA);
    gather_gemm2_kernel<<<N_NODES / 4, 256, 0, stream>>>(csr, rowptr, dis, xlA, W2, b1, xlB);
    gather_pool_kernel <<<N_NODES / 4, 256, 0, stream>>>(csr, rowptr, dis, xlB, b2, Wc, sval);
    final_out_kernel<<<N_GRAPHS, 256, 0, stream>>>(sval, batch, bc, out);
}